// Round 1
// baseline (252.078 us; speedup 1.0000x reference)
//
#include <hip/hip_runtime.h>
#include <hip/hip_bf16.h>
#include <math.h>

#define HH 4
#define BB 4
#define CC 32
#define VV 1000
#define LL 12
#define EE 20000
#define LALPHA 0.2f
#define NEG_CAP_F -9000000000000000.0f

// Kernel A: h_g[h][b][l][v][c] = sum_ci x[b,ci,v,l] * W[h,ci,c]
// Also s_src[h][b][l][v] = sum_c h*a_src[h,c], s_dst likewise.
__global__ __launch_bounds__(256) void k_h(const float* __restrict__ x,
                                           const float* __restrict__ W,
                                           const float* __restrict__ a,
                                           float* __restrict__ h_g,
                                           float* __restrict__ s_src,
                                           float* __restrict__ s_dst) {
  __shared__ float W_lds[HH * CC * CC];   // 16 KB
  __shared__ float a_lds[HH * 2 * CC];    // 1 KB
  __shared__ float x_lds[CC * 8 * LL];    // 12 KB
  const int tid = threadIdx.x;
  const int b = blockIdx.y;
  const int v0 = blockIdx.x * 8;

  for (int i = tid; i < HH * CC * CC; i += 256) W_lds[i] = W[i];
  for (int i = tid; i < HH * 2 * CC; i += 256) a_lds[i] = a[i];
  for (int i = tid; i < CC * 8 * LL; i += 256) {
    int ci = i / (8 * LL);
    int r = i - ci * (8 * LL);
    x_lds[i] = x[(b * CC + ci) * (VV * LL) + v0 * LL + r];
  }
  __syncthreads();

  const int vp = tid >> 5;   // 0..7: which v in chunk
  const int c = tid & 31;    // output channel

  float acc[HH][LL];
#pragma unroll
  for (int h = 0; h < HH; ++h)
#pragma unroll
    for (int l = 0; l < LL; ++l) acc[h][l] = 0.f;

#pragma unroll 4
  for (int ci = 0; ci < CC; ++ci) {
    float xv[LL];
#pragma unroll
    for (int l = 0; l < LL; ++l) xv[l] = x_lds[ci * (8 * LL) + vp * LL + l];
#pragma unroll
    for (int h = 0; h < HH; ++h) {
      float w = W_lds[h * CC * CC + ci * CC + c];
#pragma unroll
      for (int l = 0; l < LL; ++l) acc[h][l] = fmaf(xv[l], w, acc[h][l]);
    }
  }

  const int v = v0 + vp;
#pragma unroll
  for (int h = 0; h < HH; ++h) {
    float asrc = a_lds[h * 2 * CC + c];
    float adst = a_lds[h * 2 * CC + CC + c];
#pragma unroll
    for (int l = 0; l < LL; ++l) {
      float hv = acc[h][l];
      int slab = (h * BB + b) * LL + l;
      h_g[((size_t)slab * VV + v) * CC + c] = hv;
      float sv = hv * asrc;
      float dv = hv * adst;
#pragma unroll
      for (int m = 16; m >= 1; m >>= 1) {
        sv += __shfl_xor(sv, m);
        dv += __shfl_xor(dv, m);
      }
      if (c == 0) {
        s_src[slab * VV + v] = sv;
        s_dst[slab * VV + v] = dv;
      }
    }
  }
}

// Kernel B: build CSR keyed by e0. Single block, 1024 threads.
__global__ __launch_bounds__(1024) void k_csr(const int* __restrict__ ei,
                                              const float* __restrict__ ev,
                                              int* __restrict__ row_start,
                                              int* __restrict__ csr_dst,
                                              float* __restrict__ csr_lv) {
  __shared__ int cnt[VV];
  __shared__ int sA[1024];
  __shared__ int sB[1024];
  const int t = threadIdx.x;
  if (t < VV) cnt[t] = 0;
  __syncthreads();
  for (int e = t; e < EE; e += 1024) atomicAdd(&cnt[ei[e]], 1);
  __syncthreads();
  sA[t] = (t < VV) ? cnt[t] : 0;
  __syncthreads();
  int* pa = sA;
  int* pb = sB;
  for (int off = 1; off < 1024; off <<= 1) {
    int val = pa[t];
    if (t >= off) val += pa[t - off];
    pb[t] = val;
    __syncthreads();
    int* tmp = pa; pa = pb; pb = tmp;
  }
  // pa holds inclusive scan
  int excl = (t == 0) ? 0 : pa[t - 1];
  if (t < VV) {
    row_start[t] = excl;
    cnt[t] = excl;   // cursor
  }
  if (t == 0) row_start[VV] = pa[VV - 1];
  __syncthreads();
  for (int e = t; e < EE; e += 1024) {
    int r = ei[e];          // e0
    int d = ei[EE + e];     // e1
    int pos = atomicAdd(&cnt[r], 1);
    csr_dst[pos] = d;
    csr_lv[pos] = fmaxf(__logf(ev[e]), NEG_CAP_F);
  }
}

// Kernel C: aggregation + finalize. One wave per (v,b,l).
// lane = j*32 + c : j picks one of 2 parallel edges, c = channel.
__global__ __launch_bounds__(256) void k_agg(const float* __restrict__ h_g,
                                             const float* __restrict__ s_src,
                                             const float* __restrict__ s_dst,
                                             const int* __restrict__ row_start,
                                             const int* __restrict__ csr_dst,
                                             const float* __restrict__ csr_lv,
                                             float* __restrict__ out) {
  const int w = blockIdx.x * 4 + (threadIdx.x >> 6);
  const int lane = threadIdx.x & 63;
  const int j = lane >> 5;
  const int c = lane & 31;
  const int v = w % VV;
  const int bl = w / VV;
  const int b = bl / LL;
  const int l = bl - b * LL;

  const int start = row_start[v];
  const int end = row_start[v + 1];

  float out_acc = 0.f;
#pragma unroll
  for (int h = 0; h < HH; ++h) {
    const int slab = (h * BB + b) * LL + l;
    const float* sd = s_dst + slab * VV;
    const float* hg = h_g + (size_t)slab * VV * CC;
    const float ssv = s_src[slab * VV + v];
    float num = 0.f, rs = 0.f;
    for (int p = start + j; p < end; p += 2) {
      int dst = csr_dst[p];
      float lv = csr_lv[p];
      float sc = ssv + sd[dst];
      float lr = sc > 0.f ? sc : LALPHA * sc;
      float ee = __expf(-lr) * lv;
      num = fmaf(ee, hg[dst * CC + c], num);
      rs += ee;
    }
    num += __shfl_xor(num, 32);
    rs += __shfl_xor(rs, 32);
    out_acc += num / rs;
  }

  if (j == 0) {
    float m = out_acc * 0.25f;               // mean over H
    float r = m > 0.f ? m : expm1f(m);       // elu, alpha=1
    out[((b * CC + c) * VV + v) * LL + l] = r;
  }
}

extern "C" void kernel_launch(void* const* d_in, const int* in_sizes, int n_in,
                              void* d_out, int out_size, void* d_ws, size_t ws_size,
                              hipStream_t stream) {
  const float* x = (const float*)d_in[0];
  const float* W = (const float*)d_in[1];
  const float* a = (const float*)d_in[2];
  const int* ei = (const int*)d_in[3];
  const float* ev = (const float*)d_in[4];
  float* out = (float*)d_out;

  float* h_g = (float*)d_ws;                                   // H*B*L*V*C
  float* s_src = h_g + (size_t)HH * BB * LL * VV * CC;         // H*B*L*V
  float* s_dst = s_src + HH * BB * LL * VV;                    // H*B*L*V
  int* row_start = (int*)(s_dst + HH * BB * LL * VV);          // V+1 (pad 1024)
  int* csr_dst = row_start + 1024;                             // E
  float* csr_lv = (float*)(csr_dst + EE);                      // E

  dim3 gA(VV / 8, BB);
  k_h<<<gA, 256, 0, stream>>>(x, W, a, h_g, s_src, s_dst);
  k_csr<<<1, 1024, 0, stream>>>(ei, ev, row_start, csr_dst, csr_lv);
  const int nwaves = BB * LL * VV;  // 48000
  k_agg<<<nwaves / 4, 256, 0, stream>>>(h_g, s_src, s_dst, row_start, csr_dst, csr_lv, out);
}

// Round 2
// 99.724 us; speedup vs baseline: 2.5278x; 2.5278x over previous
//
#include <hip/hip_runtime.h>
#include <hip/hip_bf16.h>
#include <math.h>

#define HH 4
#define BB 4
#define CC 32
#define VV 1000
#define LL 12
#define EE 20000
#define SS (HH * BB * LL) /* 192 slabs */
#define LALPHA 0.2f
#define NEG_CAP_F -9000000000000000.0f

// ---------------------------------------------------------------------------
// Kernel A: h_g[slab][v][c] with slab=(h*BB+b)*LL+l,
//           h_g = sum_ci x[b,ci,v,l] * W[h,ci,c]
// Also s_src[slab][v], s_dst[slab][v] (attention logits), and zeroes cnt[].
// ---------------------------------------------------------------------------
__global__ __launch_bounds__(256) void k_h(const float* __restrict__ x,
                                           const float* __restrict__ W,
                                           const float* __restrict__ a,
                                           float* __restrict__ h_g,
                                           float* __restrict__ s_src,
                                           float* __restrict__ s_dst,
                                           int* __restrict__ cnt) {
  if (blockIdx.y == 0 && blockIdx.x < 4) {
    int z = blockIdx.x * 256 + threadIdx.x;
    if (z < VV) cnt[z] = 0;
  }

  __shared__ float W_lds[HH * CC * CC];   // 16 KB
  __shared__ float a_lds[HH * 2 * CC];    // 1 KB
  __shared__ float x_lds[CC * 8 * LL];    // 12 KB
  const int tid = threadIdx.x;
  const int b = blockIdx.y;
  const int v0 = blockIdx.x * 8;

  for (int i = tid; i < HH * CC * CC; i += 256) W_lds[i] = W[i];
  for (int i = tid; i < HH * 2 * CC; i += 256) a_lds[i] = a[i];
  for (int i = tid; i < CC * 8 * LL; i += 256) {
    int ci = i / (8 * LL);
    int r = i - ci * (8 * LL);
    x_lds[i] = x[(b * CC + ci) * (VV * LL) + v0 * LL + r];
  }
  __syncthreads();

  const int vp = tid >> 5;   // 0..7: which v in chunk
  const int c = tid & 31;    // output channel

  float acc[HH][LL];
#pragma unroll
  for (int h = 0; h < HH; ++h)
#pragma unroll
    for (int l = 0; l < LL; ++l) acc[h][l] = 0.f;

#pragma unroll 4
  for (int ci = 0; ci < CC; ++ci) {
    float xv[LL];
#pragma unroll
    for (int l = 0; l < LL; ++l) xv[l] = x_lds[ci * (8 * LL) + vp * LL + l];
#pragma unroll
    for (int h = 0; h < HH; ++h) {
      float w = W_lds[h * CC * CC + ci * CC + c];
#pragma unroll
      for (int l = 0; l < LL; ++l) acc[h][l] = fmaf(xv[l], w, acc[h][l]);
    }
  }

  const int v = v0 + vp;
#pragma unroll
  for (int h = 0; h < HH; ++h) {
    float asrc = a_lds[h * 2 * CC + c];
    float adst = a_lds[h * 2 * CC + CC + c];
#pragma unroll
    for (int l = 0; l < LL; ++l) {
      float hv = acc[h][l];
      int slab = (h * BB + b) * LL + l;
      h_g[((size_t)slab * VV + v) * CC + c] = hv;
      float sv = hv * asrc;
      float dv = hv * adst;
#pragma unroll
      for (int m = 16; m >= 1; m >>= 1) {
        sv += __shfl_xor(sv, m);
        dv += __shfl_xor(dv, m);
      }
      if (c == 0) {
        s_src[slab * VV + v] = sv;
        s_dst[slab * VV + v] = dv;
      }
    }
  }
}

// ---------------------------------------------------------------------------
// CSR build: histogram -> scan -> scatter (parallel, small kernels)
// ---------------------------------------------------------------------------
__global__ __launch_bounds__(256) void k_hist(const int* __restrict__ ei,
                                              int* __restrict__ cnt) {
  int e = blockIdx.x * 256 + threadIdx.x;
  if (e < EE) atomicAdd(&cnt[ei[e]], 1);
}

__global__ __launch_bounds__(1024) void k_scan(const int* __restrict__ cnt,
                                               int* __restrict__ row_start,
                                               int* __restrict__ cursor) {
  __shared__ int sA[1024];
  __shared__ int sB[1024];
  const int t = threadIdx.x;
  sA[t] = (t < VV) ? cnt[t] : 0;
  __syncthreads();
  int* pa = sA;
  int* pb = sB;
  for (int off = 1; off < 1024; off <<= 1) {
    int val = pa[t];
    if (t >= off) val += pa[t - off];
    pb[t] = val;
    __syncthreads();
    int* tmp = pa; pa = pb; pb = tmp;
  }
  int excl = (t == 0) ? 0 : pa[t - 1];
  if (t < VV) {
    row_start[t] = excl;
    cursor[t] = excl;
  }
  if (t == 0) row_start[VV] = pa[VV - 1];
}

__global__ __launch_bounds__(256) void k_scatter(const int* __restrict__ ei,
                                                 const float* __restrict__ ev,
                                                 int* __restrict__ cursor,
                                                 int* __restrict__ csr_dst,
                                                 int* __restrict__ csr_src,
                                                 float* __restrict__ csr_lv) {
  int e = blockIdx.x * 256 + threadIdx.x;
  if (e >= EE) return;
  int r = ei[e];
  int d = ei[EE + e];
  int pos = atomicAdd(&cursor[r], 1);
  csr_dst[pos] = d;
  if (csr_src) csr_src[pos] = r;
  csr_lv[pos] = fmaxf(__logf(ev[e]), NEG_CAP_F);
}

// ---------------------------------------------------------------------------
// ee[slab][p] = exp(-leaky(s_src[slab][src] + s_dst[slab][dst])) * lv[p]
// ---------------------------------------------------------------------------
__global__ __launch_bounds__(256) void k_ee(const int* __restrict__ csr_src,
                                            const int* __restrict__ csr_dst,
                                            const float* __restrict__ csr_lv,
                                            const float* __restrict__ s_src,
                                            const float* __restrict__ s_dst,
                                            float* __restrict__ ee) {
  const int sl = blockIdx.y;
  const int p = blockIdx.x * 256 + threadIdx.x;
  if (p >= EE) return;
  int src = csr_src[p];
  int dst = csr_dst[p];
  float lv = csr_lv[p];
  float s = s_src[sl * VV + src] + s_dst[sl * VV + dst];
  float lr = s > 0.f ? s : LALPHA * s;
  ee[(size_t)sl * EE + p] = __expf(-lr) * lv;
}

// ---------------------------------------------------------------------------
// Aggregation. One wave per (v, bl). XCD-swizzled so each (b,l) stretch of
// 250 blocks lands on one XCD (L2-resident 940 KB working set).
// lane = jj*32 + c : jj picks one of 2 parallel edges, c = channel.
// ---------------------------------------------------------------------------
template <bool USE_EE, bool USE_TMP>
__global__ __launch_bounds__(256) void k_agg(const float* __restrict__ h_g,
                                             const float* __restrict__ ee,
                                             const float* __restrict__ s_src,
                                             const float* __restrict__ s_dst,
                                             const int* __restrict__ row_start,
                                             const int* __restrict__ csr_dst,
                                             const float* __restrict__ csr_lv,
                                             float* __restrict__ outp) {
  const int i = blockIdx.x;
  const int xcd = i & 7;
  const int jb = i >> 3;                   // 0..1499
  const int bl = xcd + 8 * (jb / 250);     // 0..47, one stretch per XCD slot
  const int pis = jb % 250;
  const int warp = threadIdx.x >> 6;
  const int v = pis * 4 + warp;
  const int b = bl / LL;
  const int l = bl - b * LL;
  const int lane = threadIdx.x & 63;
  const int jj = lane >> 5;
  const int c = lane & 31;

  const int start = row_start[v];
  const int end = row_start[v + 1];

  float num[HH] = {0.f, 0.f, 0.f, 0.f};
  float rs[HH] = {0.f, 0.f, 0.f, 0.f};
  const float* hb[HH];
  const float* eb[HH];
  const float* sdb[HH];
  float ssv[HH];
#pragma unroll
  for (int h = 0; h < HH; ++h) {
    const int slab = bl + h * (BB * LL);
    hb[h] = h_g + (size_t)slab * VV * CC;
    if (USE_EE) {
      eb[h] = ee + (size_t)slab * EE;
    } else {
      sdb[h] = s_dst + slab * VV;
      ssv[h] = s_src[slab * VV + v];
    }
  }

#pragma unroll 2
  for (int p = start + jj; p < end; p += 2) {
    const int dst = csr_dst[p];
    const int hix = dst * CC + c;
    float lvv = 0.f;
    if (!USE_EE) lvv = csr_lv[p];
#pragma unroll
    for (int h = 0; h < HH; ++h) {
      float eev;
      if (USE_EE) {
        eev = eb[h][p];
      } else {
        float s = ssv[h] + sdb[h][dst];
        float lr = s > 0.f ? s : LALPHA * s;
        eev = __expf(-lr) * lvv;
      }
      num[h] = fmaf(eev, hb[h][hix], num[h]);
      rs[h] += eev;
    }
  }

  float out_acc = 0.f;
#pragma unroll
  for (int h = 0; h < HH; ++h) {
    float n = num[h] + __shfl_xor(num[h], 32);
    float r = rs[h] + __shfl_xor(rs[h], 32);
    out_acc += n / r;
  }

  if (jj == 0) {
    float m = out_acc * 0.25f;              // mean over H
    float res = m > 0.f ? m : expm1f(m);    // elu
    if (USE_TMP)
      outp[((size_t)bl * VV + v) * CC + c] = res;          // [b][l][v][c]
    else
      outp[((b * CC + c) * VV + v) * LL + l] = res;        // [b][c][v][l]
  }
}

// ---------------------------------------------------------------------------
// Transpose tmp[b][l][v][c] -> out[b][c][v][l], LDS-tiled, coalesced both ways
// ---------------------------------------------------------------------------
__global__ __launch_bounds__(256) void k_tr(const float* __restrict__ tmp,
                                            float* __restrict__ outp) {
  __shared__ float t[CC * 97];   // [c][vi*12+l], stride 97 breaks banks
  const int b = blockIdx.y;
  const int v0 = blockIdx.x * 8;
  const int tid = threadIdx.x;
#pragma unroll
  for (int k = 0; k < 12; ++k) {
    int idx = tid + k * 256;               // 0..3071
    int c = idx & 31;
    int vi = (idx >> 5) & 7;
    int l = idx >> 8;
    t[c * 97 + vi * 12 + l] =
        tmp[(((size_t)(b * LL + l)) * VV + v0 + vi) * CC + c];
  }
  __syncthreads();
#pragma unroll
  for (int k = 0; k < 12; ++k) {
    int idx = tid + k * 256;
    int c = idx / 96;
    int vl = idx - c * 96;
    outp[((size_t)(b * CC + c) * VV + v0) * LL + vl] = t[c * 97 + vl];
  }
}

// ---------------------------------------------------------------------------
extern "C" void kernel_launch(void* const* d_in, const int* in_sizes, int n_in,
                              void* d_out, int out_size, void* d_ws, size_t ws_size,
                              hipStream_t stream) {
  const float* x = (const float*)d_in[0];
  const float* W = (const float*)d_in[1];
  const float* a = (const float*)d_in[2];
  const int* ei = (const int*)d_in[3];
  const float* ev = (const float*)d_in[4];
  float* out = (float*)d_out;
  float* ws = (float*)d_ws;

  // common layout
  size_t o = 0;
  float* h_g = ws + o;   o += (size_t)SS * VV * CC;   // 24,576,000
  float* s_src = ws + o; o += (size_t)SS * VV;        // 192,000
  float* s_dst = ws + o; o += (size_t)SS * VV;        // 192,000
  float* csr_lv = ws + o; o += EE;                    // 20,000
  int* ibase = (int*)(ws + o);
  int* cnt = ibase;                 // 1024
  int* row_start = ibase + 1024;    // 1024 (uses 1001)
  int* cursor = ibase + 2048;       // 1024
  int* csr_dst = ibase + 3072;      // 20,000
  o += 23072;
  size_t o_common = o;

  // tier thresholds
  const size_t LOW_B = o_common * 4;
  const size_t MID_B = (o_common + (size_t)BB * LL * VV * CC) * 4;
  const size_t FULL_B = (o_common + 20000 + (size_t)SS * EE + (size_t)BB * LL * VV * CC) * 4;

  int tier = (ws_size >= FULL_B) ? 2 : (ws_size >= MID_B) ? 1 : 0;

  int* csr_src = nullptr;
  float* ee = nullptr;
  float* tmp = nullptr;
  if (tier == 2) {
    csr_src = ibase + 23072;  o += 20000;
    ee = ws + o;              o += (size_t)SS * EE;
    tmp = ws + o;             o += (size_t)BB * LL * VV * CC;
  } else if (tier == 1) {
    tmp = ws + o;             o += (size_t)BB * LL * VV * CC;
  }

  dim3 gA(VV / 8, BB);
  k_h<<<gA, 256, 0, stream>>>(x, W, a, h_g, s_src, s_dst, cnt);

  const int EB = (EE + 255) / 256;  // 79
  k_hist<<<EB, 256, 0, stream>>>(ei, cnt);
  k_scan<<<1, 1024, 0, stream>>>(cnt, row_start, cursor);
  k_scatter<<<EB, 256, 0, stream>>>(ei, ev, cursor, csr_dst, csr_src, csr_lv);

  const int nblk = BB * LL * VV / 4;  // 12000
  if (tier == 2) {
    k_ee<<<dim3(EB, SS), 256, 0, stream>>>(csr_src, csr_dst, csr_lv, s_src, s_dst, ee);
    k_agg<true, true><<<nblk, 256, 0, stream>>>(h_g, ee, s_src, s_dst, row_start,
                                                csr_dst, csr_lv, tmp);
    k_tr<<<dim3(VV / 8, BB), 256, 0, stream>>>(tmp, out);
  } else if (tier == 1) {
    k_agg<false, true><<<nblk, 256, 0, stream>>>(h_g, ee, s_src, s_dst, row_start,
                                                 csr_dst, csr_lv, tmp);
    k_tr<<<dim3(VV / 8, BB), 256, 0, stream>>>(tmp, out);
  } else {
    k_agg<false, false><<<nblk, 256, 0, stream>>>(h_g, ee, s_src, s_dst, row_start,
                                                  csr_dst, csr_lv, out);
  }
}